// Round 3
// baseline (729.683 us; speedup 1.0000x reference)
//
#include <hip/hip_runtime.h>
#include <hip/hip_fp16.h>
#include <stdint.h>

#define E_ 64
#define KTOP 4
#define H_ 2048
#define I_ 1536
#define GS_ 128
#define T_ 1024
#define CAP 128

typedef _Float16 f16x8 __attribute__((ext_vector_type(8)));
typedef float f32x4 __attribute__((ext_vector_type(4)));

__device__ __forceinline__ uint32_t f16pk(float a, float b) {
  __half2 h = __floats2half2_rn(a, b);
  return __builtin_bit_cast(uint32_t, h);
}
__device__ __forceinline__ uint32_t h2pk(float s) {
  uint32_t u = (uint32_t)__builtin_bit_cast(uint16_t, __float2half(s));
  return u | (u << 16);
}
__device__ __forceinline__ uint32_t pkmul(uint32_t a, uint32_t b) {
  __half2 x = __builtin_bit_cast(__half2, a);
  __half2 y = __builtin_bit_cast(__half2, b);
  __half2 r = __hmul2(x, y);
  return __builtin_bit_cast(uint32_t, r);
}

// FP4 e2m1 -> f16, times scale. Output k-order within the 8: (0,2,4,6,1,3,5,7)
// (matches the global within-8 even/odd permutation applied to all A operands).
__device__ __forceinline__ f16x8 dq_f16(uint32_t w, uint32_t spk) {
  uint32_t ev = w & 0x07070707u;
  uint32_t od = (w >> 4) & 0x07070707u;
  uint32_t se = (w << 4) & 0x80808080u;
  uint32_t so = w & 0x80808080u;
  // f16 high-byte LUT for mags {0,.5,1,1.5, 2,3,4,6}: 00,38,3C,3E / 40,42,44,46
  uint32_t he = __builtin_amdgcn_perm(0x46444240u, 0x3E3C3800u, ev) | se;
  uint32_t ho = __builtin_amdgcn_perm(0x46444240u, 0x3E3C3800u, od) | so;
  uint4 r;
  r.x = pkmul(__builtin_amdgcn_perm(he, 0u, 0x05000400u), spk);  // k0,k2
  r.y = pkmul(__builtin_amdgcn_perm(he, 0u, 0x07000600u), spk);  // k4,k6
  r.z = pkmul(__builtin_amdgcn_perm(ho, 0u, 0x05000400u), spk);  // k1,k3
  r.w = pkmul(__builtin_amdgcn_perm(ho, 0u, 0x07000600u), spk);  // k5,k7
  return __builtin_bit_cast(f16x8, r);
}

// ---------------- prep: cast x (f32 -> f16, within-8 even/odd perm) + transpose gate_w ----------------
__global__ void prep_kernel(const float* __restrict__ x, uint16_t* __restrict__ xb,
                            const float* __restrict__ gw, float* __restrict__ gwT) {
  int b = blockIdx.x;
  if (b < T_ * H_ / 8 / 256) {
    int i = b * 256 + threadIdx.x;  // one 8-group per thread
    const float4* xp = (const float4*)x;
    float4 v0 = xp[2 * i], v1 = xp[2 * i + 1];
    uint4 o;
    o.x = f16pk(v0.x, v0.z);  // k0,k2
    o.y = f16pk(v1.x, v1.z);  // k4,k6
    o.z = f16pk(v0.y, v0.w);  // k1,k3
    o.w = f16pk(v1.y, v1.w);  // k5,k7
    ((uint4*)xb)[i] = o;
  } else {
    int o = (b - T_ * H_ / 8 / 256) * 256 + threadIdx.x;  // 131072
    int k = o >> 6, e = o & 63;
    gwT[o] = gw[(long)e * H_ + k];
  }
}

// ---------------- routing: coalesced logits via gwT, then top-4 ----------------
__global__ __launch_bounds__(256) void routing_kernel(
    const float* __restrict__ x, const float* __restrict__ gwT,
    float* __restrict__ tw, int* __restrict__ ti) {
  int t = blockIdx.x;
  int tid = threadIdx.x;
  __shared__ float xs[H_];
  __shared__ float lgp[4][E_];
  const float4* xp = (const float4*)(x + (long)t * H_);
  ((float4*)xs)[tid] = xp[tid];
  ((float4*)xs)[tid + 256] = xp[tid + 256];
  __syncthreads();
  int e = tid & 63, w4 = tid >> 6;
  const float* gp = gwT + (long)w4 * 512 * E_ + e;
  const float* xw = xs + w4 * 512;
  float a0 = 0.f, a1 = 0.f, a2 = 0.f, a3 = 0.f;
#pragma unroll 4
  for (int k = 0; k < 512; k += 4) {
    a0 += xw[k]     * gp[(long)(k)     * E_];
    a1 += xw[k + 1] * gp[(long)(k + 1) * E_];
    a2 += xw[k + 2] * gp[(long)(k + 2) * E_];
    a3 += xw[k + 3] * gp[(long)(k + 3) * E_];
  }
  lgp[w4][e] = (a0 + a1) + (a2 + a3);
  __syncthreads();
  if (tid < 64) {
    int lane = tid;
    float v = lgp[0][lane] + lgp[1][lane] + lgp[2][lane] + lgp[3][lane];
    float vals[KTOP]; int ids[KTOP];
#pragma unroll
    for (int k = 0; k < KTOP; k++) {
      float bv = v; int bi = lane;
      for (int off = 32; off; off >>= 1) {
        float ov = __shfl_xor(bv, off);
        int oi = __shfl_xor(bi, off);
        if (ov > bv || (ov == bv && oi < bi)) { bv = ov; bi = oi; }
      }
      vals[k] = bv; ids[k] = bi;
      if (lane == bi) v = -3.4e38f;
    }
    if (lane == 0) {
      float m = vals[0];
      float p[KTOP]; float s = 0.f;
#pragma unroll
      for (int k = 0; k < KTOP; k++) { p[k] = expf(vals[k] - m); s += p[k]; }
      float inv = 1.f / s;
#pragma unroll
      for (int k = 0; k < KTOP; k++) {
        tw[t * KTOP + k] = p[k] * inv;
        ti[t * KTOP + k] = ids[k];
      }
    }
  }
}

// ---------------- dispatch: stable rank-within-expert + capacity ----------------
__global__ void assign_kernel(const int* __restrict__ ti, int* __restrict__ counts,
                              int* __restrict__ tlist, int* __restrict__ slot_of) {
  int e = blockIdx.x;
  int lane = threadIdx.x;  // 64
  int cnt = 0;
  for (int base = 0; base < T_ * KTOP; base += 64) {
    int a = base + lane;
    int ef = ti[a];
    unsigned long long m = __ballot(ef == e);
    if (ef == e) {
      int rank = cnt + __popcll(m & ((1ull << lane) - 1ull));
      if (rank < CAP) {
        tlist[e * CAP + rank] = a >> 2;
        slot_of[a] = e * CAP + rank;
      } else {
        slot_of[a] = -1;
      }
    }
    cnt += __popcll(m);
  }
  if (lane == 0) counts[e] = min(cnt, CAP);
}

// ---------------- FP4-dequant GEMM, B-in-register, f16 ----------------
// Grid (N/128, nE + nShared, nsets). yb<nE: expert slice; else shared M-tile.
// zs selects weight/output set (gate vs up). Tile M=128,N=128,BK=64; 4 waves 2x2,
// wave tile 64x64. A double-buffered in LDS via global_load_lds (32 KB total).
// B dequantized straight into MFMA fragments (no LDS). One barrier per K-tile.
__global__ __launch_bounds__(256, 3) void gemm_fp4_kernel(
    const uint16_t* __restrict__ A1, const uint16_t* __restrict__ A2, int ldA,
    const int* __restrict__ rowids, const int* __restrict__ counts, int nE,
    const int* __restrict__ pk_e0, const int* __restrict__ pk_e1,
    const float* __restrict__ sc_e0, const float* __restrict__ sc_e1,
    long p_stride, long s_stride,
    const int* __restrict__ pk_s0, const int* __restrict__ pk_s1,
    const float* __restrict__ sc_s0, const float* __restrict__ sc_s1,
    void* __restrict__ out_e0, void* __restrict__ out_e1,
    void* __restrict__ out_s0, void* __restrict__ out_s1,
    int K, int N, int of32_e, int of32_s, int perm_out) {
  __shared__ uint16_t As[2][128 * 64];  // 2 x 16 KB

  int bn = blockIdx.x, yb = blockIdx.y, zs = blockIdx.z;
  int tid = threadIdx.x, wave = tid >> 6, lane = tid & 63;

  const uint16_t* A;
  const int* pk;
  const float* sc;
  char* outp;
  int of32, row_base, valid;
  const int* rid = nullptr;
  if (yb < nE) {
    int e = yb;
    valid = counts[e];
    if (valid <= 0) return;
    if (valid > 128) valid = 128;
    if (rowids) rid = rowids + e * CAP;
    row_base = e * CAP;
    A = A1;
    pk = (zs ? pk_e1 : pk_e0) + (long)e * p_stride;
    sc = (zs ? sc_e1 : sc_e0) + (long)e * s_stride;
    outp = (char*)(zs ? out_e1 : out_e0);
    of32 = of32_e;
  } else {
    valid = 128;
    row_base = (yb - nE) * 128;
    A = A2;
    pk = zs ? pk_s1 : pk_s0;
    sc = zs ? sc_s1 : sc_s0;
    outp = (char*)(zs ? out_s1 : out_s0);
    of32 = of32_s;
  }

  // ---- A staging setup: 16 insts of 1KB (8 rows x 64k each); 4 per wave.
  // HW write: lane l -> byte l*16 -> row inst*8+(l>>3), slot l&7.
  // Slot c holds global chunk c ^ (r&7)  (XOR swizzle, undone on read).
  uint32_t a_off[4];
  int lds_dst[4];
#pragma unroll
  for (int ii = 0; ii < 4; ii++) {
    int inst = wave * 4 + ii;
    int r = inst * 8 + (lane >> 3);
    int rr = r < valid ? r : valid - 1;
    int arow = rid ? rid[rr] : row_base + rr;
    a_off[ii] = (uint32_t)arow * (uint32_t)ldA + (uint32_t)((((lane & 7) ^ (r & 7)) << 3));
    lds_dst[ii] = inst * 512;
  }

  int wm = wave >> 1, wn = wave & 1;
  int q = lane >> 4, r16 = lane & 15;
  int KW = K >> 3;

  // ---- B setup: lane needs cols bn*128 + wn*64 + fn*16 + r16, words 2q,2q+1 per tile.
  uint32_t bw_off[4], sc_off[4];
#pragma unroll
  for (int fn = 0; fn < 4; fn++) {
    int c = bn * 128 + wn * 64 + fn * 16 + r16;
    bw_off[fn] = (uint32_t)c * (uint32_t)KW + 2 * q;
    sc_off[fn] = (uint32_t)c;
  }

  f32x4 acc[4][4];
#pragma unroll
  for (int a0 = 0; a0 < 4; a0++)
#pragma unroll
    for (int b0 = 0; b0 < 4; b0++) {
      f32x4 z = {0.f, 0.f, 0.f, 0.f};
      acc[a0][b0] = z;
    }

  int nk = K >> 6;

#define STAGE(BUF, KT) do {                                                     \
    _Pragma("unroll") for (int ii = 0; ii < 4; ii++)                            \
      __builtin_amdgcn_global_load_lds(                                         \
          (const __attribute__((address_space(1))) unsigned int*)(A + (KT) + a_off[ii]), \
          (__attribute__((address_space(3))) unsigned int*)(&As[BUF][0] + lds_dst[ii]),  \
          16, 0, 0);                                                            \
  } while (0)

#define LOADB(BPK, SCL, KT) do {                                                \
    int ktw = (KT) >> 3;                                                        \
    int sgb = ((KT) >> 7) * N;                                                  \
    _Pragma("unroll") for (int fn = 0; fn < 4; fn++) {                          \
      BPK[fn] = *(const uint2*)(pk + ktw + bw_off[fn]);                         \
      SCL[fn] = sc[sgb + sc_off[fn]];                                           \
    }                                                                           \
  } while (0)

#define SLAB(BUF, S, BPK, SPKA) do {                                            \
    f16x8 bfr[4], af[4];                                                        \
    _Pragma("unroll") for (int fn = 0; fn < 4; fn++)                            \
      bfr[fn] = dq_f16((S) ? BPK[fn].y : BPK[fn].x, SPKA[fn]);                  \
    _Pragma("unroll") for (int fm = 0; fm < 4; fm++) {                          \
      int m = wm * 64 + fm * 16 + r16;                                          \
      int slot = (2 * q + (S)) ^ (m & 7);                                       \
      af[fm] = *(const f16x8*)(&As[BUF][0] + m * 64 + slot * 8);                \
    }                                                                           \
    _Pragma("unroll") for (int fm = 0; fm < 4; fm++)                            \
      _Pragma("unroll") for (int fn = 0; fn < 4; fn++)                          \
        acc[fm][fn] = __builtin_amdgcn_mfma_f32_16x16x32_f16(af[fm], bfr[fn], acc[fm][fn], 0, 0, 0); \
  } while (0)

#define ITER(T, BUF, BPK_C, SCL_C, BPK_N, SCL_N) do {                           \
    __builtin_amdgcn_sched_barrier(0);                                          \
    asm volatile("s_waitcnt vmcnt(0)" ::: "memory");                            \
    __builtin_amdgcn_s_barrier();                                               \
    __builtin_amdgcn_sched_barrier(0);                                          \
    if ((T) + 1 < nk) {                                                         \
      STAGE((BUF) ^ 1, ((T) + 1) << 6);                                         \
      LOADB(BPK_N, SCL_N, ((T) + 1) << 6);                                      \
    }                                                                           \
    uint32_t sp_[4];                                                            \
    _Pragma("unroll") for (int fn = 0; fn < 4; fn++) sp_[fn] = h2pk(SCL_C[fn]); \
    __builtin_amdgcn_s_setprio(1);                                              \
    SLAB(BUF, 0, BPK_C, sp_);                                                   \
    SLAB(BUF, 1, BPK_C, sp_);                                                   \
    __builtin_amdgcn_s_setprio(0);                                              \
  } while (0)

  // prologue: tile 0 in flight
  uint2 bpkA[4], bpkB[4];
  float sclA[4], sclB[4];
  STAGE(0, 0);
  LOADB(bpkA, sclA, 0);

  for (int it = 0; it < nk; it += 2) {
    ITER(it, 0, bpkA, sclA, bpkB, sclB);
    ITER(it + 1, 1, bpkB, sclB, bpkA, sclA);
  }

  // ---- epilogue: D mapping col=lane&15, row=(lane>>4)*4+reg
  int outr0 = wm * 64 + (q << 2);
  int outc0 = bn * 128 + wn * 64 + r16;
  int c7 = r16 & 7;
  int pdel = perm_out ? ((((c7 & 1) << 2) | (c7 >> 1)) - c7) : 0;
#pragma unroll
  for (int fm = 0; fm < 4; fm++)
#pragma unroll
    for (int fn = 0; fn < 4; fn++) {
#pragma unroll
      for (int r = 0; r < 4; r++) {
        int rloc = outr0 + fm * 16 + r;
        if (rloc >= valid) continue;
        long row = row_base + rloc;
        long col = outc0 + fn * 16 + pdel;
        float vv = acc[fm][fn][r];
        if (of32) ((float*)outp)[row * N + col] = vv;
        else ((uint16_t*)outp)[row * N + col] =
            __builtin_bit_cast(uint16_t, __float2half(vv));
      }
    }
#undef STAGE
#undef LOADB
#undef SLAB
#undef ITER
}

// ---------------- h = silu(g) * u  (f16, expert + shared fused) ----------------
__global__ void silu_mul_kernel(const uint16_t* __restrict__ g, const uint16_t* __restrict__ u,
                                uint16_t* __restrict__ h,
                                const uint16_t* __restrict__ gs, const uint16_t* __restrict__ us,
                                uint16_t* __restrict__ hs, int n8e, int n8s) {
  int i = blockIdx.x * blockDim.x + threadIdx.x;
  const uint16_t *G, *U;
  uint16_t* Hp;
  int idx;
  if (i < n8e) { G = g; U = u; Hp = h; idx = i; }
  else if (i < n8e + n8s) { G = gs; U = us; Hp = hs; idx = i - n8e; }
  else return;
  uint4 gv = ((const uint4*)G)[idx];
  uint4 uv = ((const uint4*)U)[idx];
  uint32_t gw[4] = {gv.x, gv.y, gv.z, gv.w};
  uint32_t uw[4] = {uv.x, uv.y, uv.z, uv.w};
  uint32_t rw[4];
#pragma unroll
  for (int w = 0; w < 4; w++) {
    float2 gf = __half22float2(__builtin_bit_cast(__half2, gw[w]));
    float2 uf = __half22float2(__builtin_bit_cast(__half2, uw[w]));
    float r0 = gf.x / (1.f + __expf(-gf.x)) * uf.x;
    float r1 = gf.y / (1.f + __expf(-gf.y)) * uf.y;
    rw[w] = f16pk(r0, r1);
  }
  uint4 res; res.x = rw[0]; res.y = rw[1]; res.z = rw[2]; res.w = rw[3];
  ((uint4*)Hp)[idx] = res;
}

// ---------------- combine: y[t] += sum_k w_k * eout[slot_k] ----------------
__global__ __launch_bounds__(256) void combine_kernel(
    float* __restrict__ y, const uint16_t* __restrict__ eout,
    const int* __restrict__ slot_of, const float* __restrict__ tw) {
  int t = blockIdx.x;
  int c = threadIdx.x * 8;
  float* yp = y + (long)t * H_ + c;
  float4 y0 = ((float4*)yp)[0];
  float4 y1 = ((float4*)yp)[1];
  float a[8] = {y0.x, y0.y, y0.z, y0.w, y1.x, y1.y, y1.z, y1.w};
#pragma unroll
  for (int k = 0; k < KTOP; k++) {
    int s = slot_of[t * KTOP + k];
    float w = tw[t * KTOP + k];
    if (s < 0) continue;
    uint4 v = *(const uint4*)(eout + (long)s * H_ + c);
    uint32_t vw[4] = {v.x, v.y, v.z, v.w};
#pragma unroll
    for (int jj = 0; jj < 4; jj++) {
      float2 f = __half22float2(__builtin_bit_cast(__half2, vw[jj]));
      a[2 * jj]     += w * f.x;
      a[2 * jj + 1] += w * f.y;
    }
  }
  float4 o0 = {a[0], a[1], a[2], a[3]};
  float4 o1 = {a[4], a[5], a[6], a[7]};
  ((float4*)yp)[0] = o0;
  ((float4*)yp)[1] = o1;
}

extern "C" void kernel_launch(void* const* d_in, const int* in_sizes, int n_in,
                              void* d_out, int out_size, void* d_ws, size_t ws_size,
                              hipStream_t stream) {
  const float* x              = (const float*)d_in[0];
  const float* gate_w         = (const float*)d_in[1];
  const float* gate_scales    = (const float*)d_in[2];
  const float* up_scales      = (const float*)d_in[3];
  const float* down_scales    = (const float*)d_in[4];
  const float* sh_gate_scales = (const float*)d_in[5];
  const float* sh_up_scales   = (const float*)d_in[6];
  const float* sh_down_scales = (const float*)d_in[7];
  const int* gate_packed      = (const int*)d_in[8];
  const int* up_packed        = (const int*)d_in[9];
  const int* down_packed      = (const int*)d_in[10];
  const int* sh_gate_packed   = (const int*)d_in[11];
  const int* sh_up_packed     = (const int*)d_in[12];
  const int* sh_down_packed   = (const int*)d_in[13];
  float* y = (float*)d_out;

  char* ws = (char*)d_ws;
  uint16_t* xb     = (uint16_t*)(ws);               // 4,194,304 B (f16, within-8 perm)
  float*    tw     = (float*)(ws + 4194304);
  int*      ti     = (int*)(ws + 4210688);
  int*      counts = (int*)(ws + 4227072);
  int*      tlist  = (int*)(ws + 4227328);
  int*      slot_of= (int*)(ws + 4260096);
  uint16_t* gbuf   = (uint16_t*)(ws + 4276480);     // 25,165,824 (later h)
  float*    gwT    = (float*)(ws + 4276480);        // 524,288 B, aliases gbuf (dead before gate GEMM)
  uint16_t* ubuf   = (uint16_t*)(ws + 29442304);    // 25,165,824
  uint16_t* eout   = (uint16_t*)(ws + 29442304);    // 33,554,432 (aliases dead ubuf)
  uint16_t* gsbuf  = (uint16_t*)(ws + 62996736);    // 3,145,728 (later hs)
  uint16_t* usbuf  = (uint16_t*)(ws + 66142464);    // 3,145,728; end ~69.3 MB

  prep_kernel<<<1536, 256, 0, stream>>>(x, xb, gate_w, gwT);
  routing_kernel<<<T_, 256, 0, stream>>>(x, gwT, tw, ti);
  assign_kernel<<<E_, 64, 0, stream>>>(ti, counts, tlist, slot_of);

  // gate+up (+ shared) fused: z=0 gate, z=1 up.  [tok] x [K=2048] -> [1536]
  gemm_fp4_kernel<<<dim3(12, 72, 2), 256, 0, stream>>>(
      xb, xb, H_, tlist, counts, E_,
      gate_packed, up_packed, gate_scales, up_scales,
      (long)I_ * (H_ / 8), (long)(H_ / GS_) * I_,
      sh_gate_packed, sh_up_packed, sh_gate_scales, sh_up_scales,
      gbuf, ubuf, gsbuf, usbuf,
      H_, I_, 0, 0, 1);

  silu_mul_kernel<<<(E_ * CAP * I_ / 8 + T_ * I_ / 8) / 256, 256, 0, stream>>>(
      gbuf, ubuf, gbuf, gsbuf, usbuf, gsbuf, E_ * CAP * I_ / 8, T_ * I_ / 8);

  // down (+ shared down -> y f32): [tok] x [K=1536] -> [2048], canonical cols
  gemm_fp4_kernel<<<dim3(16, 72, 1), 256, 0, stream>>>(
      gbuf, gsbuf, I_, nullptr, counts, E_,
      down_packed, nullptr, down_scales, nullptr,
      (long)H_ * (I_ / 8), (long)(I_ / GS_) * H_,
      sh_down_packed, nullptr, sh_down_scales, nullptr,
      eout, nullptr, y, nullptr,
      I_, H_, 0, 1, 0);

  combine_kernel<<<T_, 256, 0, stream>>>(y, eout, slot_of, tw);
}

// Round 6
// 525.375 us; speedup vs baseline: 1.3889x; 1.3889x over previous
//
#include <hip/hip_runtime.h>
#include <hip/hip_fp16.h>
#include <stdint.h>

#define E_ 64
#define KTOP 4
#define H_ 2048
#define I_ 1536
#define GS_ 128
#define T_ 1024
#define CAP 128

typedef _Float16 f16x8 __attribute__((ext_vector_type(8)));
typedef float f32x4 __attribute__((ext_vector_type(4)));

__device__ __forceinline__ uint32_t f16pk(float a, float b) {
  __half2 h = __floats2half2_rn(a, b);
  return __builtin_bit_cast(uint32_t, h);
}
__device__ __forceinline__ uint32_t h2pk(float s) {
  uint32_t u = (uint32_t)__builtin_bit_cast(uint16_t, __float2half(s));
  return u | (u << 16);
}
__device__ __forceinline__ uint32_t pkmul(uint32_t a, uint32_t b) {
  __half2 x = __builtin_bit_cast(__half2, a);
  __half2 y = __builtin_bit_cast(__half2, b);
  __half2 r = __hmul2(x, y);
  return __builtin_bit_cast(uint32_t, r);
}

// FP4 e2m1 -> f16, times scale. Output k-order within the 8: (0,2,4,6,1,3,5,7)
// (matches the global within-8 even/odd permutation applied to all A operands).
__device__ __forceinline__ uint4 dq_f16(uint32_t w, uint32_t spk) {
  uint32_t ev = w & 0x07070707u;
  uint32_t od = (w >> 4) & 0x07070707u;
  uint32_t se = (w << 4) & 0x80808080u;
  uint32_t so = w & 0x80808080u;
  // f16 high-byte LUT for mags {0,.5,1,1.5, 2,3,4,6}: 00,38,3C,3E / 40,42,44,46
  uint32_t he = __builtin_amdgcn_perm(0x46444240u, 0x3E3C3800u, ev) | se;
  uint32_t ho = __builtin_amdgcn_perm(0x46444240u, 0x3E3C3800u, od) | so;
  uint4 r;
  r.x = pkmul(__builtin_amdgcn_perm(he, 0u, 0x05000400u), spk);  // k0,k2
  r.y = pkmul(__builtin_amdgcn_perm(he, 0u, 0x07000600u), spk);  // k4,k6
  r.z = pkmul(__builtin_amdgcn_perm(ho, 0u, 0x05000400u), spk);  // k1,k3
  r.w = pkmul(__builtin_amdgcn_perm(ho, 0u, 0x07000600u), spk);  // k5,k7
  return r;
}

// ---------------- prep: cast x (f32 -> f16, within-8 even/odd perm) + transpose gate_w ----------------
__global__ void prep_kernel(const float* __restrict__ x, uint16_t* __restrict__ xb,
                            const float* __restrict__ gw, float* __restrict__ gwT) {
  int b = blockIdx.x;
  if (b < T_ * H_ / 8 / 256) {
    int i = b * 256 + threadIdx.x;  // one 8-group per thread
    const float4* xp = (const float4*)x;
    float4 v0 = xp[2 * i], v1 = xp[2 * i + 1];
    uint4 o;
    o.x = f16pk(v0.x, v0.z);  // k0,k2
    o.y = f16pk(v1.x, v1.z);  // k4,k6
    o.z = f16pk(v0.y, v0.w);  // k1,k3
    o.w = f16pk(v1.y, v1.w);  // k5,k7
    ((uint4*)xb)[i] = o;
  } else {
    int o = (b - T_ * H_ / 8 / 256) * 256 + threadIdx.x;  // 131072
    int k = o >> 6, e = o & 63;
    gwT[o] = gw[(long)e * H_ + k];
  }
}

// ---------------- routing: coalesced logits via gwT, then top-4 ----------------
__global__ __launch_bounds__(256) void routing_kernel(
    const float* __restrict__ x, const float* __restrict__ gwT,
    float* __restrict__ tw, int* __restrict__ ti) {
  int t = blockIdx.x;
  int tid = threadIdx.x;
  __shared__ float xs[H_];
  __shared__ float lgp[4][E_];
  const float4* xp = (const float4*)(x + (long)t * H_);
  ((float4*)xs)[tid] = xp[tid];
  ((float4*)xs)[tid + 256] = xp[tid + 256];
  __syncthreads();
  int e = tid & 63, w4 = tid >> 6;
  const float* gp = gwT + (long)w4 * 512 * E_ + e;
  const float* xw = xs + w4 * 512;
  float a0 = 0.f, a1 = 0.f, a2 = 0.f, a3 = 0.f;
#pragma unroll 4
  for (int k = 0; k < 512; k += 4) {
    a0 += xw[k]     * gp[(long)(k)     * E_];
    a1 += xw[k + 1] * gp[(long)(k + 1) * E_];
    a2 += xw[k + 2] * gp[(long)(k + 2) * E_];
    a3 += xw[k + 3] * gp[(long)(k + 3) * E_];
  }
  lgp[w4][e] = (a0 + a1) + (a2 + a3);
  __syncthreads();
  if (tid < 64) {
    int lane = tid;
    float v = lgp[0][lane] + lgp[1][lane] + lgp[2][lane] + lgp[3][lane];
    float vals[KTOP]; int ids[KTOP];
#pragma unroll
    for (int k = 0; k < KTOP; k++) {
      float bv = v; int bi = lane;
      for (int off = 32; off; off >>= 1) {
        float ov = __shfl_xor(bv, off);
        int oi = __shfl_xor(bi, off);
        if (ov > bv || (ov == bv && oi < bi)) { bv = ov; bi = oi; }
      }
      vals[k] = bv; ids[k] = bi;
      if (lane == bi) v = -3.4e38f;
    }
    if (lane == 0) {
      float m = vals[0];
      float p[KTOP]; float s = 0.f;
#pragma unroll
      for (int k = 0; k < KTOP; k++) { p[k] = expf(vals[k] - m); s += p[k]; }
      float inv = 1.f / s;
#pragma unroll
      for (int k = 0; k < KTOP; k++) {
        tw[t * KTOP + k] = p[k] * inv;
        ti[t * KTOP + k] = ids[k];
      }
    }
  }
}

// ---------------- dispatch: stable rank-within-expert + capacity ----------------
__global__ void assign_kernel(const int* __restrict__ ti, int* __restrict__ counts,
                              int* __restrict__ tlist, int* __restrict__ slot_of) {
  int e = blockIdx.x;
  int lane = threadIdx.x;  // 64
  int cnt = 0;
  for (int base = 0; base < T_ * KTOP; base += 64) {
    int a = base + lane;
    int ef = ti[a];
    unsigned long long m = __ballot(ef == e);
    if (ef == e) {
      int rank = cnt + __popcll(m & ((1ull << lane) - 1ull));
      if (rank < CAP) {
        tlist[e * CAP + rank] = a >> 2;
        slot_of[a] = e * CAP + rank;
      } else {
        slot_of[a] = -1;
      }
    }
    cnt += __popcll(m);
  }
  if (lane == 0) counts[e] = min(cnt, CAP);
}

// ---------------- FP4-dequant GEMM, M=64 tiles, f16, pipelined ----------------
// Grid (N/128, 2*nE + nShared64, nsets). yb<2*nE: expert tile (e=yb>>1, mt=yb&1,
// valid=counts[e]-mt*64, early exit). Else shared 64-row tile. zs selects
// weight/output set (gate vs up). Tile M=64,N=128,BK=64; 4 waves 2x2, wave tile
// 32x64, acc 2x4 (32 AGPR). A double-buffered via global_load_lds (16 KB);
// packed B prefetched coalesced to regs, dequanted into Bs (16 KB) once/block.
// 2 barriers/iter, counted vmcnt(4) keeps next tile's 4 loads in flight.
__global__ __launch_bounds__(256, 4) void gemm_fp4_kernel(
    const uint16_t* __restrict__ A1, const uint16_t* __restrict__ A2, int ldA,
    const int* __restrict__ rowids, const int* __restrict__ counts, int nE,
    const int* __restrict__ pk_e0, const int* __restrict__ pk_e1,
    const float* __restrict__ sc_e0, const float* __restrict__ sc_e1,
    long p_stride, long s_stride,
    const int* __restrict__ pk_s0, const int* __restrict__ pk_s1,
    const float* __restrict__ sc_s0, const float* __restrict__ sc_s1,
    void* __restrict__ out_e0, void* __restrict__ out_e1,
    void* __restrict__ out_s0, void* __restrict__ out_s1,
    int K, int N, int of32_e, int of32_s, int perm_out) {
  __shared__ uint16_t As[2][64 * 64];   // 2 x 8 KB
  __shared__ uint16_t Bs[8 * 128 * 8];  // 16 KB, layout [kc][n][8]

  int bn = blockIdx.x, yb = blockIdx.y, zs = blockIdx.z;
  int tid = threadIdx.x, wave = tid >> 6, lane = tid & 63;

  const uint16_t* A;
  const int* pk;
  const float* sc;
  char* outp;
  int of32, row_base, valid;
  const int* rid = nullptr;
  if (yb < 2 * nE) {
    int e = yb >> 1, mt = yb & 1;
    valid = counts[e] - mt * 64;
    if (valid <= 0) return;
    if (valid > 64) valid = 64;
    if (rowids) rid = rowids + e * CAP + mt * 64;
    row_base = e * CAP + mt * 64;
    A = A1;
    pk = (zs ? pk_e1 : pk_e0) + (long)e * p_stride;
    sc = (zs ? sc_e1 : sc_e0) + (long)e * s_stride;
    outp = (char*)(zs ? out_e1 : out_e0);
    of32 = of32_e;
  } else {
    valid = 64;
    row_base = (yb - 2 * nE) * 64;
    A = A2;
    pk = zs ? pk_s1 : pk_s0;
    sc = zs ? sc_s1 : sc_s0;
    outp = (char*)(zs ? out_s1 : out_s0);
    of32 = of32_s;
  }

  // ---- A staging: 8 insts of 1KB (8 rows x 64k each); 2 per wave.
  // HW write: lane l -> byte l*16 -> row inst*8+(l>>3), slot l&7.
  // Slot c holds global chunk c ^ (r&7)  (XOR swizzle, undone on read).
  uint32_t a_off[2];
  int lds_dst[2];
#pragma unroll
  for (int ii = 0; ii < 2; ii++) {
    int inst = wave * 2 + ii;
    int r = inst * 8 + (lane >> 3);
    int rr = r < valid ? r : valid - 1;
    int arow = rid ? rid[rr] : row_base + rr;
    a_off[ii] = (uint32_t)arow * (uint32_t)ldA + (uint32_t)(((lane & 7) ^ (r & 7)) << 3);
    lds_dst[ii] = inst * 512;
  }

  // ---- B staging: thread pair per n-row; each thread 4 packed words (32 k)/tile,
  // one coalesced 16B load, dequant to Bs fragment layout.
  int j = tid >> 1, wseg = tid & 1;
  int n_col = bn * 128 + j;
  const int* prow = pk + (long)n_col * (K >> 3) + wseg * 4;
  uint16_t* bdst = Bs + ((wseg * 4) * 128 + j) * 8;

  int wm = wave >> 1, wn = wave & 1;
  int q = lane >> 4, r16 = lane & 15;

  f32x4 acc[2][4];
#pragma unroll
  for (int a0 = 0; a0 < 2; a0++)
#pragma unroll
    for (int b0 = 0; b0 < 4; b0++) {
      f32x4 z = {0.f, 0.f, 0.f, 0.f};
      acc[a0][b0] = z;
    }

  int nk = K >> 6;

#define STAGE(BUF, KT) do {                                                     \
    _Pragma("unroll") for (int ii = 0; ii < 2; ii++)                            \
      __builtin_amdgcn_global_load_lds(                                         \
          (const __attribute__((address_space(1))) unsigned int*)(A + (KT) + a_off[ii]), \
          (__attribute__((address_space(3))) unsigned int*)(&As[BUF][0] + lds_dst[ii]),  \
          16, 0, 0);                                                            \
  } while (0)

#define LOADB(BPK, SCL, KT) do {                                                \
    BPK = *(const uint4*)(prow + ((KT) >> 3));                                  \
    SCL = sc[((KT) >> 7) * N + n_col];                                          \
  } while (0)

#define DEQB(BPK, SCL) do {                                                     \
    uint32_t spk_ = h2pk(SCL);                                                  \
    uint32_t wv_[4] = {BPK.x, BPK.y, BPK.z, BPK.w};                             \
    _Pragma("unroll") for (int i = 0; i < 4; i++)                               \
      *(uint4*)(bdst + i * 1024) = dq_f16(wv_[i], spk_);                        \
  } while (0)

#define MFMAS(BUF) do {                                                         \
    _Pragma("unroll") for (int kk = 0; kk < 64; kk += 32) {                     \
      int kc = (kk >> 3) + q;                                                   \
      f16x8 af[2], bfr[4];                                                      \
      _Pragma("unroll") for (int fm = 0; fm < 2; fm++) {                        \
        int m = wm * 32 + fm * 16 + r16;                                        \
        af[fm] = *(const f16x8*)(&As[BUF][0] + m * 64 + ((kc ^ (m & 7)) << 3)); \
      }                                                                         \
      _Pragma("unroll") for (int fn = 0; fn < 4; fn++) {                        \
        int n = wn * 64 + fn * 16 + r16;                                        \
        bfr[fn] = *(const f16x8*)(Bs + (kc * 128 + n) * 8);                     \
      }                                                                         \
      _Pragma("unroll") for (int fm = 0; fm < 2; fm++)                          \
        _Pragma("unroll") for (int fn = 0; fn < 4; fn++)                        \
          acc[fm][fn] = __builtin_amdgcn_mfma_f32_16x16x32_f16(af[fm], bfr[fn], acc[fm][fn], 0, 0, 0); \
    }                                                                           \
  } while (0)

#define ITER(T, BUF, BPK_C, SCL_C, BPK_N, SCL_N) do {                           \
    if ((T) + 1 < nk) {                                                         \
      STAGE((BUF) ^ 1, ((T) + 1) << 6);                                         \
      LOADB(BPK_N, SCL_N, ((T) + 1) << 6);                                      \
    }                                                                           \
    DEQB(BPK_C, SCL_C);                                                         \
    __builtin_amdgcn_sched_barrier(0);                                          \
    if ((T) + 1 < nk) asm volatile("s_waitcnt vmcnt(4) lgkmcnt(0)" ::: "memory"); \
    else              asm volatile("s_waitcnt vmcnt(0) lgkmcnt(0)" ::: "memory"); \
    __builtin_amdgcn_s_barrier();                                               \
    __builtin_amdgcn_sched_barrier(0);                                          \
    __builtin_amdgcn_s_setprio(1);                                              \
    MFMAS(BUF);                                                                 \
    __builtin_amdgcn_s_setprio(0);                                              \
    __builtin_amdgcn_sched_barrier(0);                                          \
    __builtin_amdgcn_s_barrier();                                               \
    __builtin_amdgcn_sched_barrier(0);                                          \
  } while (0)

  // prologue: tile 0 in flight
  uint4 bpkA, bpkB;
  float sclA, sclB;
  STAGE(0, 0);
  LOADB(bpkA, sclA, 0);

  for (int it = 0; it < nk; it += 2) {
    ITER(it, 0, bpkA, sclA, bpkB, sclB);
    ITER(it + 1, 1, bpkB, sclB, bpkA, sclA);
  }

  // ---- epilogue: D mapping col=lane&15, row=(lane>>4)*4+reg
  int outr0 = wm * 32 + (q << 2);
  int outc0 = bn * 128 + wn * 64 + r16;
  int c7 = r16 & 7;
  int pdel = perm_out ? ((((c7 & 1) << 2) | (c7 >> 1)) - c7) : 0;
#pragma unroll
  for (int fm = 0; fm < 2; fm++)
#pragma unroll
    for (int fn = 0; fn < 4; fn++) {
#pragma unroll
      for (int r = 0; r < 4; r++) {
        int rloc = outr0 + fm * 16 + r;
        if (rloc >= valid) continue;
        long row = row_base + rloc;
        long col = outc0 + fn * 16 + pdel;
        float vv = acc[fm][fn][r];
        if (of32) ((float*)outp)[row * N + col] = vv;
        else ((uint16_t*)outp)[row * N + col] =
            __builtin_bit_cast(uint16_t, __float2half(vv));
      }
    }
#undef STAGE
#undef LOADB
#undef DEQB
#undef MFMAS
#undef ITER
}

// ---------------- h = silu(g) * u  (f16, expert + shared fused) ----------------
__global__ void silu_mul_kernel(const uint16_t* __restrict__ g, const uint16_t* __restrict__ u,
                                uint16_t* __restrict__ h,
                                const uint16_t* __restrict__ gs, const uint16_t* __restrict__ us,
                                uint16_t* __restrict__ hs, int n8e, int n8s) {
  int i = blockIdx.x * blockDim.x + threadIdx.x;
  const uint16_t *G, *U;
  uint16_t* Hp;
  int idx;
  if (i < n8e) { G = g; U = u; Hp = h; idx = i; }
  else if (i < n8e + n8s) { G = gs; U = us; Hp = hs; idx = i - n8e; }
  else return;
  uint4 gv = ((const uint4*)G)[idx];
  uint4 uv = ((const uint4*)U)[idx];
  uint32_t gw[4] = {gv.x, gv.y, gv.z, gv.w};
  uint32_t uw[4] = {uv.x, uv.y, uv.z, uv.w};
  uint32_t rw[4];
#pragma unroll
  for (int w = 0; w < 4; w++) {
    float2 gf = __half22float2(__builtin_bit_cast(__half2, gw[w]));
    float2 uf = __half22float2(__builtin_bit_cast(__half2, uw[w]));
    float r0 = gf.x / (1.f + __expf(-gf.x)) * uf.x;
    float r1 = gf.y / (1.f + __expf(-gf.y)) * uf.y;
    rw[w] = f16pk(r0, r1);
  }
  uint4 res; res.x = rw[0]; res.y = rw[1]; res.z = rw[2]; res.w = rw[3];
  ((uint4*)Hp)[idx] = res;
}

// ---------------- combine: y[t] += sum_k w_k * eout[slot_k] ----------------
__global__ __launch_bounds__(256) void combine_kernel(
    float* __restrict__ y, const uint16_t* __restrict__ eout,
    const int* __restrict__ slot_of, const float* __restrict__ tw) {
  int t = blockIdx.x;
  int c = threadIdx.x * 8;
  float* yp = y + (long)t * H_ + c;
  float4 y0 = ((float4*)yp)[0];
  float4 y1 = ((float4*)yp)[1];
  float a[8] = {y0.x, y0.y, y0.z, y0.w, y1.x, y1.y, y1.z, y1.w};
#pragma unroll
  for (int k = 0; k < KTOP; k++) {
    int s = slot_of[t * KTOP + k];
    float w = tw[t * KTOP + k];
    if (s < 0) continue;
    uint4 v = *(const uint4*)(eout + (long)s * H_ + c);
    uint32_t vw[4] = {v.x, v.y, v.z, v.w};
#pragma unroll
    for (int jj = 0; jj < 4; jj++) {
      float2 f = __half22float2(__builtin_bit_cast(__half2, vw[jj]));
      a[2 * jj]     += w * f.x;
      a[2 * jj + 1] += w * f.y;
    }
  }
  float4 o0 = {a[0], a[1], a[2], a[3]};
  float4 o1 = {a[4], a[5], a[6], a[7]};
  ((float4*)yp)[0] = o0;
  ((float4*)yp)[1] = o1;
}

extern "C" void kernel_launch(void* const* d_in, const int* in_sizes, int n_in,
                              void* d_out, int out_size, void* d_ws, size_t ws_size,
                              hipStream_t stream) {
  const float* x              = (const float*)d_in[0];
  const float* gate_w         = (const float*)d_in[1];
  const float* gate_scales    = (const float*)d_in[2];
  const float* up_scales      = (const float*)d_in[3];
  const float* down_scales    = (const float*)d_in[4];
  const float* sh_gate_scales = (const float*)d_in[5];
  const float* sh_up_scales   = (const float*)d_in[6];
  const float* sh_down_scales = (const float*)d_in[7];
  const int* gate_packed      = (const int*)d_in[8];
  const int* up_packed        = (const int*)d_in[9];
  const int* down_packed      = (const int*)d_in[10];
  const int* sh_gate_packed   = (const int*)d_in[11];
  const int* sh_up_packed     = (const int*)d_in[12];
  const int* sh_down_packed   = (const int*)d_in[13];
  float* y = (float*)d_out;

  char* ws = (char*)d_ws;
  uint16_t* xb     = (uint16_t*)(ws);               // 4,194,304 B (f16, within-8 perm)
  float*    tw     = (float*)(ws + 4194304);
  int*      ti     = (int*)(ws + 4210688);
  int*      counts = (int*)(ws + 4227072);
  int*      tlist  = (int*)(ws + 4227328);
  int*      slot_of= (int*)(ws + 4260096);
  uint16_t* gbuf   = (uint16_t*)(ws + 4276480);     // 25,165,824 (later h)
  float*    gwT    = (float*)(ws + 4276480);        // 524,288 B, aliases gbuf (dead before gate GEMM)
  uint16_t* ubuf   = (uint16_t*)(ws + 29442304);    // 25,165,824
  uint16_t* eout   = (uint16_t*)(ws + 29442304);    // 33,554,432 (aliases dead ubuf)
  uint16_t* gsbuf  = (uint16_t*)(ws + 62996736);    // 3,145,728 (later hs)
  uint16_t* usbuf  = (uint16_t*)(ws + 66142464);    // 3,145,728; end ~69.3 MB

  prep_kernel<<<1536, 256, 0, stream>>>(x, xb, gate_w, gwT);
  routing_kernel<<<T_, 256, 0, stream>>>(x, gwT, tw, ti);
  assign_kernel<<<E_, 64, 0, stream>>>(ti, counts, tlist, slot_of);

  // gate+up (+ shared) fused: z=0 gate, z=1 up.  [tok] x [K=2048] -> [1536]
  // y-grid: 128 expert 64-row tiles + 16 shared 64-row tiles = 144
  gemm_fp4_kernel<<<dim3(12, 144, 2), 256, 0, stream>>>(
      xb, xb, H_, tlist, counts, E_,
      gate_packed, up_packed, gate_scales, up_scales,
      (long)I_ * (H_ / 8), (long)(H_ / GS_) * I_,
      sh_gate_packed, sh_up_packed, sh_gate_scales, sh_up_scales,
      gbuf, ubuf, gsbuf, usbuf,
      H_, I_, 0, 0, 1);

  silu_mul_kernel<<<(E_ * CAP * I_ / 8 + T_ * I_ / 8) / 256, 256, 0, stream>>>(
      gbuf, ubuf, gbuf, gsbuf, usbuf, gsbuf, E_ * CAP * I_ / 8, T_ * I_ / 8);

  // down (+ shared down -> y f32): [tok] x [K=1536] -> [2048], canonical cols
  gemm_fp4_kernel<<<dim3(16, 144, 1), 256, 0, stream>>>(
      gbuf, gsbuf, I_, nullptr, counts, E_,
      down_packed, nullptr, down_scales, nullptr,
      (long)H_ * (I_ / 8), (long)(I_ / GS_) * H_,
      sh_down_packed, nullptr, sh_down_scales, nullptr,
      eout, nullptr, y, nullptr,
      I_, H_, 0, 1, 0);

  combine_kernel<<<T_, 256, 0, stream>>>(y, eout, slot_of, tw);
}